// Round 9
// baseline (101.057 us; speedup 1.0000x reference)
//
#include <hip/hip_runtime.h>
#include <math.h>

#define BN 1024   // batch
#define CN 512    // clusters
#define DN 256    // dims
#define RB 4      // batch rows per block; grid = BN/RB = 256 = 1 block/CU
#define KCH 16    // d-chunk staged per iteration
#define NCH (DN / KCH)   // 16 chunks
#define WSTR 17   // padded LDS row stride (odd => conflict-free b128, 17 mod 32 bijective)

#define NEG_INF_F (-1e30f)

__device__ __forceinline__ float waveMax(float v) {
    #pragma unroll
    for (int off = 32; off > 0; off >>= 1) v = fmaxf(v, __shfl_xor(v, off));
    return v;
}
__device__ __forceinline__ float waveSum(float v) {
    #pragma unroll
    for (int off = 32; off > 0; off >>= 1) v += __shfl_xor(v, off);
    return v;
}

// ---------------------------------------------------------------------------
// Single fused kernel. Per block: 4 batch rows x all 512 clusters.
//  - s_d = sqrt(attn_d / sum attn) computed redundantly per block (1 KB).
//  - w staged coalesced global->LDS in 16-d chunks, scaled by s_d at stage
//    time, double-buffered (stage z+1 overlaps compute z, 1 barrier/chunk).
//  - lane owns 8 clusters (c = lane + 64j); wave wz covers d-range
//    [16z+4*wz, +4) per chunk; acc[4][8] in registers.
//  - cross-wave combine via LDS (reuses w buffer), then wave rr runs the
//    whole double softmax + readout for row rr fully in-wave (R7-verified).
// ---------------------------------------------------------------------------
__launch_bounds__(256, 1)
__global__ void clus_kernel(const float* __restrict__ inp, const float* __restrict__ wd,
                            const float* __restrict__ attn, const float* __restrict__ w_assoc,
                            const int* __restrict__ mask, float* __restrict__ y) {
    __shared__ __align__(16) float wbuf[2][CN * WSTR];  // 69632 B
    __shared__ __align__(16) float xs[RB][DN];          // 4 KB (s-scaled input rows)
    __shared__ __align__(16) float sarr[DN];            // 1 KB  sqrt(a_d)
    __shared__ float red4[4];

    const int tid  = threadIdx.x;
    const int lane = tid & 63;
    const int wz   = __builtin_amdgcn_readfirstlane(tid >> 6);  // wave id 0..3
    const int b0   = blockIdx.x * RB;

    // ---- attention normalization (redundant per block) ----
    const float av = attn[tid];                 // 256 threads == DN
    float ssum = av;
    #pragma unroll
    for (int off = 32; off > 0; off >>= 1) ssum += __shfl_xor(ssum, off);
    if (lane == 0) red4[wz] = ssum;
    __syncthreads();
    const float total = red4[0] + red4[1] + red4[2] + red4[3];
    sarr[tid] = sqrtf(av / total);
    __syncthreads();

    // ---- stage s-scaled input rows (coalesced, once) ----
    #pragma unroll
    for (int i = 0; i < RB; ++i)
        xs[i][tid] = inp[(b0 + i) * DN + tid] * sarr[tid];
    // (xs readers wait at the prologue barrier below)

    // ---- staging helper params: thread -> (4 rows x) 1 float4 per row-quad ----
    const int col4  = (tid & 3) * 4;            // d-offset within chunk: 0,4,8,12
    const int rbase = tid >> 2;                 // 0..63

    // prologue: stage chunk 0 into buffer 0
    {
        const float4 sv = *(const float4*)&sarr[col4];
        #pragma unroll
        for (int p = 0; p < 8; ++p) {
            const int row = rbase + 64 * p;
            float4 w4 = *(const float4*)&wd[row * DN + col4];
            w4.x *= sv.x; w4.y *= sv.y; w4.z *= sv.z; w4.w *= sv.w;
            *(float4*)&wbuf[0][row * WSTR + col4] = w4;
        }
    }
    __syncthreads();

    float acc[RB][8] = {};
    const int kk = wz << 2;                     // wave's d-offset within chunk

    for (int z = 0; z < NCH; ++z) {
        // stage next chunk into the other buffer (no barrier needed here:
        // writes go to buf (z+1)&1 while compute reads buf z&1)
        if (z + 1 < NCH) {
            const int k0 = (z + 1) * KCH;
            const float4 sv = *(const float4*)&sarr[k0 + col4];
            float* dst = &wbuf[(z + 1) & 1][0];
            #pragma unroll
            for (int p = 0; p < 8; ++p) {
                const int row = rbase + 64 * p;
                float4 w4 = *(const float4*)&wd[row * DN + k0 + col4];
                w4.x *= sv.x; w4.y *= sv.y; w4.z *= sv.z; w4.w *= sv.w;
                *(float4*)&dst[row * WSTR + col4] = w4;
            }
        }
        // compute on current buffer: 4 d x 8 clusters x 4 rows
        {
            const float* wsrc = &wbuf[z & 1][0];
            float4 xv[RB];
            #pragma unroll
            for (int rr = 0; rr < RB; ++rr)
                xv[rr] = *(const float4*)&xs[rr][z * KCH + kk];   // broadcast read
            #pragma unroll
            for (int j = 0; j < 8; ++j) {
                const float4 w4 = *(const float4*)&wsrc[(lane + 64 * j) * WSTR + kk];
                #pragma unroll
                for (int rr = 0; rr < RB; ++rr) {
                    float d0 = xv[rr].x - w4.x; acc[rr][j] = fmaf(d0, d0, acc[rr][j]);
                    float d1 = xv[rr].y - w4.y; acc[rr][j] = fmaf(d1, d1, acc[rr][j]);
                    float d2 = xv[rr].z - w4.z; acc[rr][j] = fmaf(d2, d2, acc[rr][j]);
                    float d3 = xv[rr].w - w4.w; acc[rr][j] = fmaf(d3, d3, acc[rr][j]);
                }
            }
        }
        __syncthreads();   // next-chunk staging complete; current buffer free
    }

    // ---- cross-wave combine (reuse wbuf as scratch: 4*32*64 floats = 32 KB) ----
    float* comb = &wbuf[0][0];
    #pragma unroll
    for (int rr = 0; rr < RB; ++rr)
        #pragma unroll
        for (int j = 0; j < 8; ++j)
            comb[(wz * 32 + rr * 8 + j) * 64 + lane] = acc[rr][j];
    __syncthreads();

    // wave rr finishes batch row b0+rr entirely in-wave
    const int rr = wz;
    float dist[8] = {};
    #pragma unroll
    for (int zz = 0; zz < 4; ++zz)
        #pragma unroll
        for (int j = 0; j < 8; ++j)
            dist[j] += comb[(zz * 32 + rr * 8 + j) * 64 + lane];

    float t[8]; bool rec[8];
    #pragma unroll
    for (int j = 0; j < 8; ++j) {
        t[j] = sqrtf(dist[j]);
        rec[j] = mask[lane + 64 * j] > 0;
    }

    // softmax #1: logits -3*t  (= BETA*log H / TEMP_COMP, H = exp(-t))
    float l1[8], lmax = NEG_INF_F;
    #pragma unroll
    for (int j = 0; j < 8; ++j) { l1[j] = rec[j] ? (-3.0f * t[j]) : NEG_INF_F; lmax = fmaxf(lmax, l1[j]); }
    const float mx1 = waveMax(lmax);
    float e1[8], lsum = 0.f;
    #pragma unroll
    for (int j = 0; j < 8; ++j) { e1[j] = rec[j] ? expf(l1[j] - mx1) : 0.f; lsum += e1[j]; }
    const float inv_s1 = 1.0f / waveSum(lsum);

    float competed[8];
    #pragma unroll
    for (int j = 0; j < 8; ++j) competed[j] = e1[j] * inv_s1 * expf(-t[j]);

    // softmax #2: logits competed / 0.1
    float l2[8]; lmax = NEG_INF_F;
    #pragma unroll
    for (int j = 0; j < 8; ++j) { l2[j] = rec[j] ? (competed[j] * 10.0f) : NEG_INF_F; lmax = fmaxf(lmax, l2[j]); }
    const float mx2 = waveMax(lmax);
    float e2[8]; lsum = 0.f;
    #pragma unroll
    for (int j = 0; j < 8; ++j) { e2[j] = rec[j] ? expf(l2[j] - mx2) : 0.f; lsum += e2[j]; }
    const float inv_s2 = 1.0f / waveSum(lsum);

    // readout y = 1.5 * (softwta @ w_assoc)   (w_assoc reads lane-coalesced)
    float y0 = 0.f, y1 = 0.f;
    #pragma unroll
    for (int j = 0; j < 8; ++j) {
        const float sw = e2[j] * inv_s2 * competed[j];
        const float2 wa = *(const float2*)&w_assoc[2 * (lane + 64 * j)];
        y0 = fmaf(sw, wa.x, y0);
        y1 = fmaf(sw, wa.y, y1);
    }
    y0 = waveSum(y0);
    y1 = waveSum(y1);
    if (lane == 0) {
        float2 o = {1.5f * y0, 1.5f * y1};
        *(float2*)&y[(b0 + rr) * 2] = o;
    }
}

extern "C" void kernel_launch(void* const* d_in, const int* in_sizes, int n_in,
                              void* d_out, int out_size, void* d_ws, size_t ws_size,
                              hipStream_t stream) {
    const float* inp     = (const float*)d_in[0];  // [B, D]
    const float* w_dist  = (const float*)d_in[1];  // [C, D]
    const float* attn    = (const float*)d_in[2];  // [D]
    const float* w_assoc = (const float*)d_in[3];  // [C, 2]
    const int*   mask    = (const int*)d_in[4];    // [C]
    float* out = (float*)d_out;                    // [B, 2]

    clus_kernel<<<BN / RB, 256, 0, stream>>>(inp, w_dist, attn, w_assoc, mask, out);
}

// Round 12
// 74.701 us; speedup vs baseline: 1.3528x; 1.3528x over previous
//
#include <hip/hip_runtime.h>
#include <math.h>

#define BN 1024   // batch
#define CN 512    // clusters
#define DN 256    // dims
#define ROWS 4    // batch rows per dist block; grid = 256
#define DW 32     // d-slice per wave (8 waves x 32 d = 256)

// ws layout (floats): xs[BN*DN] | wT[DN*CN]
#define XS_OFF 0
#define WT_OFF (BN * DN)

#define NEG_INF_F (-1e30f)

__device__ __forceinline__ float waveMax(float v) {
    #pragma unroll
    for (int off = 32; off > 0; off >>= 1) v = fmaxf(v, __shfl_xor(v, off));
    return v;
}
__device__ __forceinline__ float waveSum(float v) {
    #pragma unroll
    for (int off = 32; off > 0; off >>= 1) v += __shfl_xor(v, off);
    return v;
}

// ---------------------------------------------------------------------------
// prep: s_d = sqrt(attn_d / sum attn);
//   blocks 0..255:   xs[r][d] = s_d * x[r][d] for 4 rows each (coalesced)
//   blocks 256..287: wT[d][c] = s_d * w[c][d], 64x64 tile transpose via LDS
// ---------------------------------------------------------------------------
__launch_bounds__(256, 4)
__global__ void prep_kernel(const float* __restrict__ inp, const float* __restrict__ wd,
                            const float* __restrict__ attn, float* __restrict__ ws) {
    __shared__ float red4[4];
    __shared__ float sarr[DN];
    __shared__ __align__(16) float tile[64][65];

    const int tid  = threadIdx.x;          // == d index, 256 threads
    const int lane = tid & 63;

    float av = attn[tid];
    float s = av;
    #pragma unroll
    for (int off = 32; off > 0; off >>= 1) s += __shfl_xor(s, off);
    if (lane == 0) red4[tid >> 6] = s;
    __syncthreads();
    const float sv = sqrtf(av / (red4[0] + red4[1] + red4[2] + red4[3]));
    sarr[tid] = sv;
    __syncthreads();

    const int blk = blockIdx.x;
    if (blk < BN / 4) {
        // 4 input rows, scaled by s_d (coalesced b32 in/out)
        #pragma unroll
        for (int i = 0; i < 4; ++i) {
            const int r = blk * 4 + i;
            ws[XS_OFF + r * DN + tid] = inp[r * DN + tid] * sv;
        }
    } else {
        // transpose tile: c0..c0+63 x d0..d0+63
        const int tb = blk - BN / 4;            // 0..31
        const int c0 = (tb & 7) * 64;
        const int d0 = (tb >> 3) * 64;
        const int cr = tid >> 2;                // 0..63
        const int q  = tid & 3;
        #pragma unroll
        for (int i = 0; i < 4; ++i) {
            const int dd = q * 16 + i * 4;
            float4 w4 = *(const float4*)&wd[(c0 + cr) * DN + d0 + dd];
            w4.x *= sarr[d0 + dd + 0]; w4.y *= sarr[d0 + dd + 1];
            w4.z *= sarr[d0 + dd + 2]; w4.w *= sarr[d0 + dd + 3];
            *(float4*)&tile[cr][dd] = w4;
        }
        __syncthreads();
        const int dr = tid >> 2;                // 0..63
        #pragma unroll
        for (int i = 0; i < 4; ++i) {
            const int cc = q * 16 + i * 4;
            float4 o = {tile[cc + 0][dr], tile[cc + 1][dr],
                        tile[cc + 2][dr], tile[cc + 3][dr]};
            *(float4*)&ws[WT_OFF + (d0 + dr) * CN + c0 + cc] = o;
        }
    }
}

// ---------------------------------------------------------------------------
// dist+softmax fused. Block: 4 batch rows x all 512 clusters, 512 threads.
// Wave wz owns d-slice [32wz, 32wz+32); lane owns clusters {4L..4L+3} and
// {256+4L..256+4L+3} read as two coalesced b128 from wT (L2-hot, no LDS!).
// x is wave-uniform (readfirstlane'd index). Pure sub+fma k-loop, no barriers.
// One 64 KB LDS combine, then wave rr finishes row b0+rr in-wave (R9 path).
// ---------------------------------------------------------------------------
__launch_bounds__(512, 1)
__global__ void dist_kernel(const float* __restrict__ ws, const int* __restrict__ mask,
                            const float* __restrict__ w_assoc, float* __restrict__ y) {
    __shared__ float comb[8 * 32 * 64];   // 64 KB: [wz][rr*8+j][lane]

    const int tid  = threadIdx.x;
    const int lane = tid & 63;
    const int wz   = __builtin_amdgcn_readfirstlane(tid >> 6);  // 0..7
    const int b0   = blockIdx.x * ROWS;

    const float* xs = ws + XS_OFF;
    const float* wT = ws + WT_OFF;
    const int d0w = wz * DW;

    float acc[ROWS][8] = {};

    #pragma unroll
    for (int ch = 0; ch < DW / 4; ++ch) {
        const int d0 = d0w + ch * 4;
        float4 xv[ROWS];
        #pragma unroll
        for (int rr = 0; rr < ROWS; ++rr) {
            const int idx = __builtin_amdgcn_readfirstlane((b0 + rr) * DN + d0);
            xv[rr] = *(const float4*)&xs[idx];
        }
        #pragma unroll
        for (int dd = 0; dd < 4; ++dd) {
            const float* wrow = &wT[(size_t)(d0 + dd) * CN];
            const float4 wa = *(const float4*)&wrow[4 * lane];         // clusters 4L..4L+3
            const float4 wb = *(const float4*)&wrow[256 + 4 * lane];   // clusters 256+4L..
            #pragma unroll
            for (int rr = 0; rr < ROWS; ++rr) {
                const float xu = (dd == 0) ? xv[rr].x : (dd == 1) ? xv[rr].y
                               : (dd == 2) ? xv[rr].z : xv[rr].w;
                float e;
                e = xu - wa.x; acc[rr][0] = fmaf(e, e, acc[rr][0]);
                e = xu - wa.y; acc[rr][1] = fmaf(e, e, acc[rr][1]);
                e = xu - wa.z; acc[rr][2] = fmaf(e, e, acc[rr][2]);
                e = xu - wa.w; acc[rr][3] = fmaf(e, e, acc[rr][3]);
                e = xu - wb.x; acc[rr][4] = fmaf(e, e, acc[rr][4]);
                e = xu - wb.y; acc[rr][5] = fmaf(e, e, acc[rr][5]);
                e = xu - wb.z; acc[rr][6] = fmaf(e, e, acc[rr][6]);
                e = xu - wb.w; acc[rr][7] = fmaf(e, e, acc[rr][7]);
            }
        }
    }

    // cross-wave combine (lane-contiguous, conflict-free)
    #pragma unroll
    for (int rr = 0; rr < ROWS; ++rr)
        #pragma unroll
        for (int j = 0; j < 8; ++j)
            comb[(wz * 32 + rr * 8 + j) * 64 + lane] = acc[rr][j];
    __syncthreads();

    if (wz < ROWS) {
        const int rr = wz;                 // wave finishes batch row b0+rr
        float dist[8] = {};
        #pragma unroll
        for (int zz = 0; zz < 8; ++zz)
            #pragma unroll
            for (int j = 0; j < 8; ++j)
                dist[j] += comb[(zz * 32 + rr * 8 + j) * 64 + lane];

        // lane's clusters: j=0..3 -> 4*lane+j ; j=4..7 -> 256+4*lane+(j-4)
        float t[8]; bool rec[8];
        const int4 m0 = *(const int4*)&mask[4 * lane];
        const int4 m1 = *(const int4*)&mask[256 + 4 * lane];
        rec[0] = m0.x > 0; rec[1] = m0.y > 0; rec[2] = m0.z > 0; rec[3] = m0.w > 0;
        rec[4] = m1.x > 0; rec[5] = m1.y > 0; rec[6] = m1.z > 0; rec[7] = m1.w > 0;
        #pragma unroll
        for (int j = 0; j < 8; ++j) t[j] = sqrtf(dist[j]);

        // softmax #1: logits -3*t (= BETA*log H / TEMP_COMP, H = exp(-t))
        float l1[8], lmax = NEG_INF_F;
        #pragma unroll
        for (int j = 0; j < 8; ++j) { l1[j] = rec[j] ? (-3.0f * t[j]) : NEG_INF_F; lmax = fmaxf(lmax, l1[j]); }
        const float mx1 = waveMax(lmax);
        float e1[8], lsum = 0.f;
        #pragma unroll
        for (int j = 0; j < 8; ++j) { e1[j] = rec[j] ? expf(l1[j] - mx1) : 0.f; lsum += e1[j]; }
        const float inv_s1 = 1.0f / waveSum(lsum);

        float competed[8];
        #pragma unroll
        for (int j = 0; j < 8; ++j) competed[j] = e1[j] * inv_s1 * expf(-t[j]);

        // softmax #2: logits competed / 0.1
        float l2[8]; lmax = NEG_INF_F;
        #pragma unroll
        for (int j = 0; j < 8; ++j) { l2[j] = rec[j] ? (competed[j] * 10.0f) : NEG_INF_F; lmax = fmaxf(lmax, l2[j]); }
        const float mx2 = waveMax(lmax);
        float e2[8]; lsum = 0.f;
        #pragma unroll
        for (int j = 0; j < 8; ++j) { e2[j] = rec[j] ? expf(l2[j] - mx2) : 0.f; lsum += e2[j]; }
        const float inv_s2 = 1.0f / waveSum(lsum);

        // readout y = 1.5 * (softwta @ w_assoc)
        const float4 waA = *(const float4*)&w_assoc[8 * lane];        // c=4L, 4L+1
        const float4 waB = *(const float4*)&w_assoc[8 * lane + 4];    // c=4L+2, 4L+3
        const float4 waC = *(const float4*)&w_assoc[512 + 8 * lane];  // c=256+4L, +1
        const float4 waD = *(const float4*)&w_assoc[512 + 8 * lane + 4];
        float sw[8];
        #pragma unroll
        for (int j = 0; j < 8; ++j) sw[j] = e2[j] * inv_s2 * competed[j];
        float y0 = 0.f, y1 = 0.f;
        y0 = fmaf(sw[0], waA.x, y0); y1 = fmaf(sw[0], waA.y, y1);
        y0 = fmaf(sw[1], waA.z, y0); y1 = fmaf(sw[1], waA.w, y1);
        y0 = fmaf(sw[2], waB.x, y0); y1 = fmaf(sw[2], waB.y, y1);
        y0 = fmaf(sw[3], waB.z, y0); y1 = fmaf(sw[3], waB.w, y1);
        y0 = fmaf(sw[4], waC.x, y0); y1 = fmaf(sw[4], waC.y, y1);
        y0 = fmaf(sw[5], waC.z, y0); y1 = fmaf(sw[5], waC.w, y1);
        y0 = fmaf(sw[6], waD.x, y0); y1 = fmaf(sw[6], waD.y, y1);
        y0 = fmaf(sw[7], waD.z, y0); y1 = fmaf(sw[7], waD.w, y1);
        y0 = waveSum(y0);
        y1 = waveSum(y1);
        if (lane == 0) {
            float2 o = {1.5f * y0, 1.5f * y1};
            *(float2*)&y[(b0 + rr) * 2] = o;
        }
    }
}

extern "C" void kernel_launch(void* const* d_in, const int* in_sizes, int n_in,
                              void* d_out, int out_size, void* d_ws, size_t ws_size,
                              hipStream_t stream) {
    const float* inp     = (const float*)d_in[0];  // [B, D]
    const float* w_dist  = (const float*)d_in[1];  // [C, D]
    const float* attn    = (const float*)d_in[2];  // [D]
    const float* w_assoc = (const float*)d_in[3];  // [C, 2]
    const int*   mask    = (const int*)d_in[4];    // [C]
    float* out = (float*)d_out;                    // [B, 2]
    float* ws  = (float*)d_ws;                     // 1.5 MB used

    prep_kernel<<<BN / 4 + 32, 256, 0, stream>>>(inp, w_dist, attn, ws);
    dist_kernel<<<BN / ROWS, 512, 0, stream>>>(ws, mask, w_assoc, out);
}

// Round 13
// 74.136 us; speedup vs baseline: 1.3631x; 1.0076x over previous
//
#include <hip/hip_runtime.h>
#include <math.h>

#define BN 1024   // batch
#define CN 512    // clusters
#define DN 256    // dims
#define ROWS 4    // batch rows per dist block; grid = 256
#define DW 32     // d-slice per wave (8 waves x 32 d = 256)

// ws layout (floats): xs[BN*DN] (a*x) | r[BN] | q[CN] | wT[DN*CN] (unscaled w^T)
#define XS_OFF 0
#define R_OFF  (BN * DN)
#define Q_OFF  (R_OFF + BN)
#define WT_OFF (Q_OFF + CN)    // 263680 floats, 16B-aligned

#define NEG_INF_F (-1e30f)

__device__ __forceinline__ float waveMax(float v) {
    #pragma unroll
    for (int off = 32; off > 0; off >>= 1) v = fmaxf(v, __shfl_xor(v, off));
    return v;
}
__device__ __forceinline__ float waveSum(float v) {
    #pragma unroll
    for (int off = 32; off > 0; off >>= 1) v += __shfl_xor(v, off);
    return v;
}

// ---------------------------------------------------------------------------
// prep: a_d = attn_d / sum(attn).
//  blk < 1024:          xs[b][d] = a_d*x ; r[b] = sum a_d x^2
//  1024 <= blk < 1536:  q[c] = sum a_d w^2
//  blk >= 1536 (32):    wT[d][c] = w[c][d]  (64x64 tile transpose, unscaled)
// ---------------------------------------------------------------------------
__launch_bounds__(256, 4)
__global__ void prep_kernel(const float* __restrict__ inp, const float* __restrict__ wd,
                            const float* __restrict__ attn, float* __restrict__ ws) {
    __shared__ float red4[4];
    __shared__ __align__(16) float tile[64][65];

    const int tid  = threadIdx.x;          // == d index, 256 threads
    const int lane = tid & 63;
    const int blk  = blockIdx.x;

    float av = attn[tid];
    float s = av;
    #pragma unroll
    for (int off = 32; off > 0; off >>= 1) s += __shfl_xor(s, off);
    if (lane == 0) red4[tid >> 6] = s;
    __syncthreads();
    const float a = av / (red4[0] + red4[1] + red4[2] + red4[3]);
    __syncthreads();                       // red4 reused below

    if (blk < BN) {
        const float x = inp[blk * DN + tid];
        ws[XS_OFF + blk * DN + tid] = a * x;
        float c = a * x * x;
        #pragma unroll
        for (int off = 32; off > 0; off >>= 1) c += __shfl_xor(c, off);
        if (lane == 0) red4[tid >> 6] = c;
        __syncthreads();
        if (tid == 0) ws[R_OFF + blk] = red4[0] + red4[1] + red4[2] + red4[3];
    } else if (blk < BN + CN) {
        const float w = wd[(blk - BN) * DN + tid];
        float c = a * w * w;
        #pragma unroll
        for (int off = 32; off > 0; off >>= 1) c += __shfl_xor(c, off);
        if (lane == 0) red4[tid >> 6] = c;
        __syncthreads();
        if (tid == 0) ws[Q_OFF + (blk - BN)] = red4[0] + red4[1] + red4[2] + red4[3];
    } else {
        // transpose tile: clusters c0..c0+63 x dims d0..d0+63
        const int tb = blk - (BN + CN);         // 0..31
        const int c0 = (tb & 7) * 64;
        const int d0 = (tb >> 3) * 64;
        const int cr = tid >> 2;                // 0..63
        const int qq = tid & 3;
        #pragma unroll
        for (int i = 0; i < 4; ++i) {
            const int dd = qq * 16 + i * 4;
            *(float4*)&tile[cr][dd] = *(const float4*)&wd[(c0 + cr) * DN + d0 + dd];
        }
        __syncthreads();
        const int dr = tid >> 2;                // 0..63
        #pragma unroll
        for (int i = 0; i < 4; ++i) {
            const int cc = qq * 16 + i * 4;
            float4 o = {tile[cc + 0][dr], tile[cc + 1][dr],
                        tile[cc + 2][dr], tile[cc + 3][dr]};
            *(float4*)&ws[WT_OFF + (d0 + dr) * CN + c0 + cc] = o;
        }
    }
}

// ---------------------------------------------------------------------------
// dist+softmax fused (R12 skeleton, expansion inner loop).
// Block: 4 batch rows x all 512 clusters, 512 threads. Wave wz owns d-slice
// [32wz,+32); lane owns clusters {4L..4L+3, 256+4L..+3} via two coalesced
// b128 reads of wT per d (L2-hot). x is wave-uniform (s_load). Inner loop is
// pure v_fmac(acc, s_xu, v_w) - 1 VALU/element. One LDS combine + barrier,
// then wave rr finishes row b0+rr fully in-wave.
// ---------------------------------------------------------------------------
__launch_bounds__(512, 1)
__global__ void dist_kernel(const float* __restrict__ ws, const int* __restrict__ mask,
                            const float* __restrict__ w_assoc, float* __restrict__ y) {
    __shared__ float comb[8 * 32 * 64];   // 64 KB: [wz][rr*8+j][lane]

    const int tid  = threadIdx.x;
    const int lane = tid & 63;
    const int wz   = __builtin_amdgcn_readfirstlane(tid >> 6);  // 0..7
    const int b0   = blockIdx.x * ROWS;

    const float* xs = ws + XS_OFF;
    const float* wT = ws + WT_OFF;
    const int d0w = wz * DW;

    float dot[ROWS][8] = {};

    #pragma unroll
    for (int ch = 0; ch < DW / 4; ++ch) {
        const int d0 = d0w + ch * 4;
        float4 xv[ROWS];
        #pragma unroll
        for (int rr = 0; rr < ROWS; ++rr) {
            const int idx = __builtin_amdgcn_readfirstlane((b0 + rr) * DN + d0);
            xv[rr] = *(const float4*)&xs[idx];
        }
        #pragma unroll
        for (int dd = 0; dd < 4; ++dd) {
            const float* wrow = &wT[(size_t)(d0 + dd) * CN];
            const float4 wa = *(const float4*)&wrow[4 * lane];         // c = 4L..4L+3
            const float4 wb = *(const float4*)&wrow[256 + 4 * lane];   // c = 256+4L..
            #pragma unroll
            for (int rr = 0; rr < ROWS; ++rr) {
                const float xu = (dd == 0) ? xv[rr].x : (dd == 1) ? xv[rr].y
                               : (dd == 2) ? xv[rr].z : xv[rr].w;
                dot[rr][0] = fmaf(xu, wa.x, dot[rr][0]);
                dot[rr][1] = fmaf(xu, wa.y, dot[rr][1]);
                dot[rr][2] = fmaf(xu, wa.z, dot[rr][2]);
                dot[rr][3] = fmaf(xu, wa.w, dot[rr][3]);
                dot[rr][4] = fmaf(xu, wb.x, dot[rr][4]);
                dot[rr][5] = fmaf(xu, wb.y, dot[rr][5]);
                dot[rr][6] = fmaf(xu, wb.z, dot[rr][6]);
                dot[rr][7] = fmaf(xu, wb.w, dot[rr][7]);
            }
        }
    }

    // cross-wave combine (lane-contiguous, conflict-free)
    #pragma unroll
    for (int rr = 0; rr < ROWS; ++rr)
        #pragma unroll
        for (int j = 0; j < 8; ++j)
            comb[(wz * 32 + rr * 8 + j) * 64 + lane] = dot[rr][j];
    __syncthreads();

    if (wz < ROWS) {
        const int rr = wz;                 // wave finishes batch row b0+rr
        float dsum[8] = {};
        #pragma unroll
        for (int zz = 0; zz < 8; ++zz)
            #pragma unroll
            for (int j = 0; j < 8; ++j)
                dsum[j] += comb[(zz * 32 + rr * 8 + j) * 64 + lane];

        const float rb = ws[R_OFF + b0 + rr];                   // uniform s_load
        const float4 q0 = *(const float4*)&ws[Q_OFF + 4 * lane];
        const float4 q1 = *(const float4*)&ws[Q_OFF + 256 + 4 * lane];
        const float qv[8] = {q0.x, q0.y, q0.z, q0.w, q1.x, q1.y, q1.z, q1.w};

        // lane's clusters: j=0..3 -> 4L+j ; j=4..7 -> 256+4L+(j-4)
        float t[8]; bool rec[8];
        const int4 m0 = *(const int4*)&mask[4 * lane];
        const int4 m1 = *(const int4*)&mask[256 + 4 * lane];
        rec[0] = m0.x > 0; rec[1] = m0.y > 0; rec[2] = m0.z > 0; rec[3] = m0.w > 0;
        rec[4] = m1.x > 0; rec[5] = m1.y > 0; rec[6] = m1.z > 0; rec[7] = m1.w > 0;
        #pragma unroll
        for (int j = 0; j < 8; ++j)
            t[j] = sqrtf(fmaxf(rb + qv[j] - 2.0f * dsum[j], 0.0f));

        // softmax #1: logits -3*t (= BETA*log H / TEMP_COMP, H = exp(-t))
        float l1[8], lmax = NEG_INF_F;
        #pragma unroll
        for (int j = 0; j < 8; ++j) { l1[j] = rec[j] ? (-3.0f * t[j]) : NEG_INF_F; lmax = fmaxf(lmax, l1[j]); }
        const float mx1 = waveMax(lmax);
        float e1[8], lsum = 0.f;
        #pragma unroll
        for (int j = 0; j < 8; ++j) { e1[j] = rec[j] ? expf(l1[j] - mx1) : 0.f; lsum += e1[j]; }
        const float inv_s1 = 1.0f / waveSum(lsum);

        float competed[8];
        #pragma unroll
        for (int j = 0; j < 8; ++j) competed[j] = e1[j] * inv_s1 * expf(-t[j]);

        // softmax #2: logits competed / 0.1
        float l2[8]; lmax = NEG_INF_F;
        #pragma unroll
        for (int j = 0; j < 8; ++j) { l2[j] = rec[j] ? (competed[j] * 10.0f) : NEG_INF_F; lmax = fmaxf(lmax, l2[j]); }
        const float mx2 = waveMax(lmax);
        float e2[8]; lsum = 0.f;
        #pragma unroll
        for (int j = 0; j < 8; ++j) { e2[j] = rec[j] ? expf(l2[j] - mx2) : 0.f; lsum += e2[j]; }
        const float inv_s2 = 1.0f / waveSum(lsum);

        // readout y = 1.5 * (softwta @ w_assoc)
        const float4 waA = *(const float4*)&w_assoc[8 * lane];        // c=4L, 4L+1
        const float4 waB = *(const float4*)&w_assoc[8 * lane + 4];    // c=4L+2, 4L+3
        const float4 waC = *(const float4*)&w_assoc[512 + 8 * lane];  // c=256+4L, +1
        const float4 waD = *(const float4*)&w_assoc[512 + 8 * lane + 4];
        float sw[8];
        #pragma unroll
        for (int j = 0; j < 8; ++j) sw[j] = e2[j] * inv_s2 * competed[j];
        float y0 = 0.f, y1 = 0.f;
        y0 = fmaf(sw[0], waA.x, y0); y1 = fmaf(sw[0], waA.y, y1);
        y0 = fmaf(sw[1], waA.z, y0); y1 = fmaf(sw[1], waA.w, y1);
        y0 = fmaf(sw[2], waB.x, y0); y1 = fmaf(sw[2], waB.y, y1);
        y0 = fmaf(sw[3], waB.z, y0); y1 = fmaf(sw[3], waB.w, y1);
        y0 = fmaf(sw[4], waC.x, y0); y1 = fmaf(sw[4], waC.y, y1);
        y0 = fmaf(sw[5], waC.z, y0); y1 = fmaf(sw[5], waC.w, y1);
        y0 = fmaf(sw[6], waD.x, y0); y1 = fmaf(sw[6], waD.y, y1);
        y0 = fmaf(sw[7], waD.z, y0); y1 = fmaf(sw[7], waD.w, y1);
        y0 = waveSum(y0);
        y1 = waveSum(y1);
        if (lane == 0) {
            float2 o = {1.5f * y0, 1.5f * y1};
            *(float2*)&y[(b0 + rr) * 2] = o;
        }
    }
}

extern "C" void kernel_launch(void* const* d_in, const int* in_sizes, int n_in,
                              void* d_out, int out_size, void* d_ws, size_t ws_size,
                              hipStream_t stream) {
    const float* inp     = (const float*)d_in[0];  // [B, D]
    const float* w_dist  = (const float*)d_in[1];  // [C, D]
    const float* attn    = (const float*)d_in[2];  // [D]
    const float* w_assoc = (const float*)d_in[3];  // [C, 2]
    const int*   mask    = (const int*)d_in[4];    // [C]
    float* out = (float*)d_out;                    // [B, 2]
    float* ws  = (float*)d_ws;                     // ~1.6 MB used

    prep_kernel<<<BN + CN + 32, 256, 0, stream>>>(inp, w_dist, attn, ws);
    dist_kernel<<<BN / ROWS, 512, 0, stream>>>(ws, mask, w_assoc, out);
}